// Round 4
// baseline (143.949 us; speedup 1.0000x reference)
//
#include <hip/hip_runtime.h>
#include <hip/hip_fp16.h>
#include <stdint.h>

// ---------------------------------------------------------------------------
// MEASUREMENT ROUND: kan_main launched 5x (idempotent full-overwrite of out)
// to expose its duration via the bench delta: dur = base + 4*main_dur.
// Kernel bodies identical to R3.
//
// BareKANLayer: out[b,o] = sum_d PCHIP_interp(x[b,d]; coeffs[o,d,:]) + bias[o]
// B=8192, O=64, D=64, K=64, grid [-2,2], h = 4/63.
// Table: per (d, interval i, o) cubic coeffs packed fp16 in uint2; row 63 is
// the linear right-extrapolation row; left extrapolation reuses row 0.
// Layout: T[d][i][o], 32 KB per d-slice, 2 MB total in d_ws.
// ---------------------------------------------------------------------------

typedef _Float16 half2v __attribute__((ext_vector_type(2)));

#if defined(__has_builtin)
#if __has_builtin(__builtin_amdgcn_fdot2)
#define HAS_FDOT2 1
#endif
#endif

__device__ __forceinline__ uint32_t h16(float f) {
    return (uint32_t)__half_as_ushort(__float2half(f));   // RNE cvt
}

__device__ __forceinline__ float dot2acc(uint32_t a_bits, uint32_t b_bits, float acc) {
    half2v a = __builtin_bit_cast(half2v, a_bits);
    half2v b = __builtin_bit_cast(half2v, b_bits);
#ifdef HAS_FDOT2
    return __builtin_amdgcn_fdot2(a, b, acc, false);
#else
    return acc + (float)a.x * (float)b.x + (float)a.y * (float)b.y;
#endif
}

// Grid: 256 blocks (d = bx>>2, o-quarter = bx&3), 256 threads.
__global__ void build_table(const float* __restrict__ coeffs, uint2* __restrict__ T) {
    const float hf = 4.0f / 63.0f;
    const float inv_hf = 63.0f / 4.0f;   // 15.75 exact in fp32
    int d  = blockIdx.x >> 2;
    int ob = (blockIdx.x & 3) << 4;      // base of this block's 16 o's
    __shared__ float Y[16][65];          // +1 pad: conflict-free
    int t = threadIdx.x;
    {
        int ol = t >> 4;                 // 0..15  (o local)
        int k4 = (t & 15) << 2;          // 0,4,...,60
        const float* src = coeffs + (size_t)(ob + ol) * 4096 + d * 64 + k4;
        float4 v = *(const float4*)src;  // 16B aligned
        Y[ol][k4 + 0] = v.x; Y[ol][k4 + 1] = v.y;
        Y[ol][k4 + 2] = v.z; Y[ol][k4 + 3] = v.w;
    }
    __syncthreads();
    for (int c = t; c < 1024; c += 256) {
        int ol = c & 15;
        int i  = c >> 4;                 // 0..63 (63 = linear extrapolation row)
        const float* Yr = Y[ol];
        auto delt = [&](int k) -> float { return (Yr[k + 1] - Yr[k]) * inv_hf; };
        auto endslope = [&](float a, float b) -> float {
            float de = (3.0f * a - b) * 0.5f;
            de = (de * a <= 0.0f) ? 0.0f : de;
            de = ((a * b < 0.0f) && (fabsf(de) > 3.0f * fabsf(a))) ? 3.0f * a : de;
            return de;
        };
        auto slope = [&](int k) -> float {
            if (k == 0)  return endslope(delt(0), delt(1));
            if (k == 63) return endslope(delt(62), delt(61));
            float dp = delt(k - 1), dn = delt(k);
            return (dp * dn > 0.0f) ? (2.0f * dp * dn) / (dp + dn + 1e-12f) : 0.0f;
        };
        uint2 pk;
        if (i < 63) {
            float y0 = Yr[i], y1 = Yr[i + 1];
            float di = slope(i), dj = slope(i + 1);
            float c0 = y0;
            float c1 = hf * di;
            float c2 = 3.0f * (y1 - y0) - hf * (2.0f * di + dj);
            float c3 = 2.0f * (y0 - y1) + hf * (di + dj);
            pk.x = (h16(c1) << 16) | h16(c0);
            pk.y = (h16(c3) << 16) | h16(c2);
        } else {
            float yN = Yr[63];
            float dN = slope(63);
            pk.x = (h16(hf * dN) << 16) | h16(yN);
            pk.y = 0u;
        }
        T[(size_t)d * 4096 + i * 64 + (ob + ol)] = pk;
    }
}

// Grid: 1024 blocks x 256 threads (4 waves). Block owns 8 b's; wave wv owns
// b_local {2wv, 2wv+1}. lane = o.
__global__ void __launch_bounds__(256) kan_main(const float* __restrict__ x,
                                                const float* __restrict__ bias,
                                                const char* __restrict__ Tb,
                                                float* __restrict__ out) {
    __shared__ uint4 WL[512];            // 8 KB: 8 b's x 64 d records
    int t    = threadIdx.x;
    int lane = t & 63;
    int wv   = t >> 6;
    int bx   = blockIdx.x;

    // ---- weight records for the block's 8 b's (2 per thread) ----
    #pragma unroll
    for (int r = 0; r < 2; ++r) {
        int idx = t + r * 256;                   // (b_local = idx>>6, d = idx&63)
        float xv = x[bx * 512 + idx];
        float tt = (xv + 2.0f) * 15.75f;
        int i = (int)floorf(tt);
        i = i < 0 ? 0 : (i > 62 ? 62 : i);
        float u = tt - (float)i;
        float w1, w2, w3; uint32_t off;
        if (xv < -2.0f)      { w1 = tt;          w2 = 0.f;    w3 = 0.f;    off = 0u; }
        else if (xv > 2.0f)  { w1 = tt - 63.0f;  w2 = 0.f;    w3 = 0.f;    off = 63u << 9; }
        else                 { w1 = u;           w2 = u * u;  w3 = w2 * u; off = (uint32_t)i << 9; }
        half2v wa; wa.x = (_Float16)1.0f; wa.y = (_Float16)w1;
        half2v wb; wb.x = (_Float16)w2;   wb.y = (_Float16)w3;
        uint32_t full_off = ((uint32_t)(idx & 63) << 15) | off;   // d*32768 + i*512
        WL[idx] = make_uint4(__builtin_bit_cast(uint32_t, wa),
                             __builtin_bit_cast(uint32_t, wb), full_off, 0u);
    }
    __syncthreads();

    // ---- accumulate over d, two b's per wave ----
    float a0 = bias[lane], b0acc = 0.0f;
    float a1 = a0,         b1acc = 0.0f;
    int laneoff = lane << 3;
    const uint4* wl0 = &WL[(wv * 2 + 0) << 6];
    const uint4* wl1 = &WL[(wv * 2 + 1) << 6];
    #pragma unroll 4
    for (int d = 0; d < 64; ++d) {
        uint4 q0 = wl0[d];                       // uniform -> LDS broadcast
        uint4 q1 = wl1[d];
        uint2 c0 = *(const uint2*)(Tb + (q0.z + laneoff));   // VGPR off + SGPR base
        uint2 c1 = *(const uint2*)(Tb + (q1.z + laneoff));
        a0    = dot2acc(q0.x, c0.x, a0);
        b0acc = dot2acc(q0.y, c0.y, b0acc);
        a1    = dot2acc(q1.x, c1.x, a1);
        b1acc = dot2acc(q1.y, c1.y, b1acc);
    }
    int bbase = bx * 8 + wv * 2;
    out[(bbase + 0) * 64 + lane] = a0 + b0acc;
    out[(bbase + 1) * 64 + lane] = a1 + b1acc;
}

extern "C" void kernel_launch(void* const* d_in, const int* in_sizes, int n_in,
                              void* d_out, int out_size, void* d_ws, size_t ws_size,
                              hipStream_t stream) {
    const float* x      = (const float*)d_in[0];   // [8192, 64]
    const float* coeffs = (const float*)d_in[1];   // [64, 64, 64]
    const float* bias   = (const float*)d_in[2];   // [64]
    float* out = (float*)d_out;                    // [8192, 64]

    uint2* T = (uint2*)d_ws;                       // 2 MB table
    build_table<<<dim3(256), dim3(256), 0, stream>>>(coeffs, T);
    // MEASUREMENT: 5 idempotent launches; bench delta vs R3 = 4 x main_dur.
    // (Same work every call; full overwrite of out; graph-capture-safe.)
    for (int rep = 0; rep < 5; ++rep) {
        kan_main<<<dim3(1024), dim3(256), 0, stream>>>(x, bias, (const char*)d_ws, out);
    }
}

// Round 5
// 78.745 us; speedup vs baseline: 1.8280x; 1.8280x over previous
//
#include <hip/hip_runtime.h>
#include <hip/hip_fp16.h>
#include <stdint.h>

// ---------------------------------------------------------------------------
// BareKANLayer: out[b,o] = sum_d PCHIP_interp(x[b,d]; coeffs[o,d,:]) + bias[o]
// B=8192, O=64, D=64, K=64, grid [-2,2], h = 4/63.
//
// Table: per (d, interval i, o) cubic coeffs of p(u) = c0 + c1 u + c2 u^2 + c3 u^3
// packed fp16 in a uint2: .x = (h(c1)<<16)|h(c0), .y = (h(c3)<<16)|h(c2).
// Row i=63 = LINEAR right-extrapolation row: .x = (h(h*dN)<<16)|h(yN), .y = 0.
// Left extrapolation reuses row 0 with w2=w3=0. T[d][i][o], 32 KB/slice, 2 MB ws.
//
// kan_main (R5): one wave per b, NO LDS. lane=d computes its weight record in
// VGPRs; the d-loop broadcasts lane d's record via v_readlane -> SGPRs (R4
// measured the old ds_read_b128 broadcast at ~10 us of LDS pipe time). Gather
// stays lane=o coalesced 512 B from the L2-resident table; weights enter
// v_dot2_f32_f16 as the SGPR operand.
// ---------------------------------------------------------------------------

typedef _Float16 half2v __attribute__((ext_vector_type(2)));

#if defined(__has_builtin)
#if __has_builtin(__builtin_amdgcn_fdot2)
#define HAS_FDOT2 1
#endif
#endif

__device__ __forceinline__ uint32_t h16(float f) {
    return (uint32_t)__half_as_ushort(__float2half(f));   // RNE cvt
}

__device__ __forceinline__ float dot2acc(uint32_t a_bits, uint32_t b_bits, float acc) {
    half2v a = __builtin_bit_cast(half2v, a_bits);
    half2v b = __builtin_bit_cast(half2v, b_bits);
#ifdef HAS_FDOT2
    return __builtin_amdgcn_fdot2(a, b, acc, false);
#else
    return acc + (float)a.x * (float)b.x + (float)a.y * (float)b.y;
#endif
}

// Grid: 256 blocks (d = bx>>2, o-quarter = bx&3), 256 threads.
__global__ void build_table(const float* __restrict__ coeffs, uint2* __restrict__ T) {
    const float hf = 4.0f / 63.0f;
    const float inv_hf = 63.0f / 4.0f;   // 15.75 exact in fp32
    int d  = blockIdx.x >> 2;
    int ob = (blockIdx.x & 3) << 4;      // base of this block's 16 o's
    __shared__ float Y[16][65];          // +1 pad: conflict-free
    int t = threadIdx.x;
    {
        int ol = t >> 4;                 // 0..15  (o local)
        int k4 = (t & 15) << 2;          // 0,4,...,60
        const float* src = coeffs + (size_t)(ob + ol) * 4096 + d * 64 + k4;
        float4 v = *(const float4*)src;  // 16B aligned
        Y[ol][k4 + 0] = v.x; Y[ol][k4 + 1] = v.y;
        Y[ol][k4 + 2] = v.z; Y[ol][k4 + 3] = v.w;
    }
    __syncthreads();
    for (int c = t; c < 1024; c += 256) {
        int ol = c & 15;
        int i  = c >> 4;                 // 0..63 (63 = linear extrapolation row)
        const float* Yr = Y[ol];
        auto delt = [&](int k) -> float { return (Yr[k + 1] - Yr[k]) * inv_hf; };
        auto endslope = [&](float a, float b) -> float {
            float de = (3.0f * a - b) * 0.5f;
            de = (de * a <= 0.0f) ? 0.0f : de;
            de = ((a * b < 0.0f) && (fabsf(de) > 3.0f * fabsf(a))) ? 3.0f * a : de;
            return de;
        };
        auto slope = [&](int k) -> float {
            if (k == 0)  return endslope(delt(0), delt(1));
            if (k == 63) return endslope(delt(62), delt(61));
            float dp = delt(k - 1), dn = delt(k);
            return (dp * dn > 0.0f) ? (2.0f * dp * dn) / (dp + dn + 1e-12f) : 0.0f;
        };
        uint2 pk;
        if (i < 63) {
            float y0 = Yr[i], y1 = Yr[i + 1];
            float di = slope(i), dj = slope(i + 1);
            float c0 = y0;
            float c1 = hf * di;
            float c2 = 3.0f * (y1 - y0) - hf * (2.0f * di + dj);
            float c3 = 2.0f * (y0 - y1) + hf * (di + dj);
            pk.x = (h16(c1) << 16) | h16(c0);
            pk.y = (h16(c3) << 16) | h16(c2);
        } else {
            float yN = Yr[63];
            float dN = slope(63);
            pk.x = (h16(hf * dN) << 16) | h16(yN);
            pk.y = 0u;
        }
        T[(size_t)d * 4096 + i * 64 + (ob + ol)] = pk;
    }
}

// Grid: 2048 blocks x 256 threads (4 waves). Wave wv owns b = bx*4 + wv.
// lane = d for the record phase, lane = o for the gather/dot phase. No LDS.
__global__ void __launch_bounds__(256) kan_main(const float* __restrict__ x,
                                                const float* __restrict__ bias,
                                                const char* __restrict__ Tb,
                                                float* __restrict__ out) {
    int t    = threadIdx.x;
    int lane = t & 63;
    int wv   = t >> 6;
    int b    = blockIdx.x * 4 + wv;

    // ---- weight record for (b, d=lane), kept in 3 VGPRs ----
    uint32_t ra, rb, roff;
    {
        float xv = x[b * 64 + lane];              // coalesced
        float tt = (xv + 2.0f) * 15.75f;
        int i = (int)floorf(tt);
        i = i < 0 ? 0 : (i > 62 ? 62 : i);
        float u = tt - (float)i;
        float w1, w2, w3; uint32_t off;
        if (xv < -2.0f)      { w1 = tt;          w2 = 0.f;    w3 = 0.f;    off = 0u; }
        else if (xv > 2.0f)  { w1 = tt - 63.0f;  w2 = 0.f;    w3 = 0.f;    off = 63u << 9; }
        else                 { w1 = u;           w2 = u * u;  w3 = w2 * u; off = (uint32_t)i << 9; }
        ra   = (h16(w1) << 16) | 0x3C00u;          // h2(1.0, w1)
        rb   = (h16(w3) << 16) | h16(w2);          // h2(w2, w3)
        roff = ((uint32_t)lane << 15) | off;       // d*32768 + i*512
    }

    // ---- accumulate over d: readlane broadcast -> SGPR, coalesced gather ----
    float acc0 = bias[lane];
    float acc1 = 0.0f;
    int laneoff = lane << 3;
    #pragma unroll
    for (int d = 0; d < 64; ++d) {
        uint32_t off = (uint32_t)__builtin_amdgcn_readlane((int)roff, d);  // SGPR
        uint32_t wa  = (uint32_t)__builtin_amdgcn_readlane((int)ra,   d);  // SGPR
        uint32_t wb  = (uint32_t)__builtin_amdgcn_readlane((int)rb,   d);  // SGPR
        uint2 c = *(const uint2*)(Tb + off + laneoff);   // SGPR base + lane off
        acc0 = dot2acc(wa, c.x, acc0);
        acc1 = dot2acc(wb, c.y, acc1);
    }
    out[b * 64 + lane] = acc0 + acc1;
}

extern "C" void kernel_launch(void* const* d_in, const int* in_sizes, int n_in,
                              void* d_out, int out_size, void* d_ws, size_t ws_size,
                              hipStream_t stream) {
    const float* x      = (const float*)d_in[0];   // [8192, 64]
    const float* coeffs = (const float*)d_in[1];   // [64, 64, 64]
    const float* bias   = (const float*)d_in[2];   // [64]
    float* out = (float*)d_out;                    // [8192, 64]

    uint2* T = (uint2*)d_ws;                       // 2 MB table
    build_table<<<dim3(256), dim3(256), 0, stream>>>(coeffs, T);
    kan_main<<<dim3(2048), dim3(256), 0, stream>>>(x, bias, (const char*)d_ws, out);
}